// Round 6
// baseline (250.791 us; speedup 1.0000x reference)
//
#include <hip/hip_runtime.h>
#include <hip/hip_bf16.h>

// B=2048, NF=64, FD=32, S=32, D=32, OD=32
typedef __attribute__((ext_vector_type(4)))  _Float16 h4;
typedef __attribute__((ext_vector_type(8)))  _Float16 h8;
typedef __attribute__((ext_vector_type(4)))  float f32x4;
typedef __attribute__((ext_vector_type(16))) float f32x16;

// Device-wide barrier. Safe: grid=512, 64KB LDS + launch_bounds(256,2) =>
// exactly 2 blocks/CU x 256 CU = all 512 co-resident by construction.
__device__ __forceinline__ void gridbar(unsigned* c) {
    __threadfence();
    __syncthreads();
    if (threadIdx.x == 0) {
        __hip_atomic_fetch_add(c, 1u, __ATOMIC_ACQ_REL, __HIP_MEMORY_SCOPE_AGENT);
        const unsigned nb = gridDim.x;
        while (__hip_atomic_load(c, __ATOMIC_ACQUIRE, __HIP_MEMORY_SCOPE_AGENT) < nb)
            __builtin_amdgcn_s_sleep(8);
    }
    __syncthreads();
    __threadfence();
}

__global__ __launch_bounds__(256, 2) void fused_kernel(
    const float* __restrict__ x, const float* __restrict__ Lg,
    const float* __restrict__ Rg, const float* __restrict__ Og,
    const float* __restrict__ bias, float* __restrict__ out,
    _Float16* __restrict__ Rb, char* __restrict__ Opp, char* __restrict__ Tp,
    unsigned* __restrict__ bar)
{
    __shared__ __align__(16) char smem[65536];

    const int bid = blockIdx.x;
    const int t = threadIdx.x, wid = t >> 6, l = t & 63;

    //================ P1: convert/transpose R -> Rb, O -> Opp ================
    // one old 64-thread conv block per wave: obid = bid*4 + wid (0..2047)
    {
        const int obid = bid*4 + wid;
        const int which = obid >> 10;              // block-uniform (bid<256 -> 0)
        const int s = obid & 31, q = (obid >> 5) & 31;
        float (*tile)[33] = (float (*)[33])(smem + wid*4352);
        const int tl = l & 31, th = l >> 5;

        if (which == 0) {
            // tile[n][a] = R[s, g=q][a][n]; Rb[s][g][n][a] f16
            #pragma unroll
            for (int j = 0; j < 16; ++j) {
                int ar = 2*j + th;
                tile[tl][ar] = Rg[(((size_t)s*32 + q)*32 + ar)*32 + tl];
            }
            __syncthreads();
            _Float16* dst = Rb + ((size_t)s*32 + q)*1024;
            #pragma unroll
            for (int it = 0; it < 4; ++it) {
                int nr = it*8 + (l >> 3), a0 = (l & 7)*4;
                h4 w;
                #pragma unroll
                for (int k = 0; k < 4; ++k) w[k] = (_Float16)tile[nr][a0 + k];
                *(h4*)(dst + nr*32 + a0) = w;
            }
        } else {
            // tile[o][n] = O[s][m=q][n][o]; Opp[s][c8][o][kk]
            #pragma unroll
            for (int j = 0; j < 16; ++j) {
                int nr = 2*j + th;
                tile[tl][nr] = Og[(((size_t)s*32 + q)*32 + nr)*32 + tl];
            }
            __syncthreads();
            char* dst = Opp + (size_t)s*65536 + q*2048;
            int o = l & 31, cq = l >> 5;
            #pragma unroll
            for (int it = 0; it < 2; ++it) {
                int c = it*2 + cq;
                h8 w;
                #pragma unroll
                for (int k = 0; k < 8; ++k) w[k] = (_Float16)tile[o][c*8 + k];
                *(h8*)(dst + c*512 + o*16) = w;
            }
        }
    }
    gridbar(bar);

    //================ P2: tmake — Tp[s][ks=f*2+gt][o][kk], 2 f per block ======
    {
        const int s = bid & 31, fpair = bid >> 5;
        const int llo = l & 15, lhi = l >> 4;
        const int ot = wid & 1, kq = wid >> 1;
        const int orow = ot*16 + llo;
        const _Float16* Rbs = Rb + (size_t)s*32768;
        const char* Opps = Opp + (size_t)s*65536;
        char* Wl = smem;

        #pragma unroll
        for (int it = 0; it < 2; ++it) {
            const int f = fpair*2 + it;
            if (it) __syncthreads();               // Wl reuse across f

            // L-frag (B-side of GEMM1)
            const float* Lsf = Lg + ((size_t)s*32 + f)*1024;
            h8 bfr[2];
            #pragma unroll
            for (int mt = 0; mt < 2; ++mt)
                #pragma unroll
                for (int j = 0; j < 8; ++j)
                    bfr[mt][j] = (_Float16)Lsf[(8*lhi + j)*32 + mt*16 + llo];

            // GEMM1: W[gn, m] = sum_a Rb[gn,a] * L[a,m]
            #pragma unroll 4
            for (int nt = 0; nt < 16; ++nt) {
                int gnb = (wid*16 + nt)*16;
                h8 af = *(const h8*)(Rbs + (gnb + llo)*32 + 8*lhi);
                int g = gnb >> 5;
                int nbase = (gnb & 31) + 4*lhi;
                #pragma unroll
                for (int mt = 0; mt < 2; ++mt) {
                    f32x4 d = __builtin_amdgcn_mfma_f32_16x16x32_f16(af, bfr[mt], (f32x4)(0.f), 0, 0, 0);
                    int m = mt*16 + llo;
                    h4 w;
                    #pragma unroll
                    for (int r = 0; r < 4; ++r) w[r] = (_Float16)d[r];
                    int byte = (g*2048 + m*64 + nbase*2) ^ ((((g & 7) ^ (m & 7))) << 4);
                    *(h4*)(Wl + byte) = w;
                }
            }
            __syncthreads();

            // GEMM2: T[g,o] = sum_mn W[g,mn] * Opp[o,mn] (kq 2-way k-split)
            f32x4 acc0 = (f32x4)(0.f), acc1 = (f32x4)(0.f);
            #pragma unroll 4
            for (int ksl = 0; ksl < 16; ++ksl) {
                int ks = kq*16 + ksl;
                h8 bf = *(const h8*)(Opps + (ks*4 + lhi)*512 + orow*16);
                {
                    int grow = llo;
                    int byte = (grow*2048 + ks*64 + lhi*16) ^ ((((grow & 7) ^ (ks & 7))) << 4);
                    h8 af = *(const h8*)(Wl + byte);
                    acc0 = __builtin_amdgcn_mfma_f32_16x16x32_f16(af, bf, acc0, 0, 0, 0);
                }
                {
                    int grow = 16 + llo;
                    int byte = (grow*2048 + ks*64 + lhi*16) ^ ((((grow & 7) ^ (ks & 7))) << 4);
                    h8 af = *(const h8*)(Wl + byte);
                    acc1 = __builtin_amdgcn_mfma_f32_16x16x32_f16(af, bf, acc1, 0, 0, 0);
                }
            }
            __syncthreads();
            if (kq == 1) {
                *(f32x4*)(Wl + ((ot*2 + 0)*64 + l)*16) = acc0;
                *(f32x4*)(Wl + ((ot*2 + 1)*64 + l)*16) = acc1;
            }
            __syncthreads();
            if (kq == 0) {
                acc0 += *(const f32x4*)(Wl + ((ot*2 + 0)*64 + l)*16);
                acc1 += *(const f32x4*)(Wl + ((ot*2 + 1)*64 + l)*16);
                char* Tps = Tp + (size_t)s*65536;
                h4 w0, w1;
                #pragma unroll
                for (int r = 0; r < 4; ++r) { w0[r] = (_Float16)acc0[r]; w1[r] = (_Float16)acc1[r]; }
                *(h4*)(Tps + (f*2 + 0)*1024 + orow*32 + lhi*8) = w0;
                *(h4*)(Tps + (f*2 + 1)*1024 + orow*32 + lhi*8) = w1;
            }
        }
    }

    //================ P3: main ================
    const int s = bid & 31;
    const int b0 = (bid >> 5) * 128;
    const int lo5 = l & 31, hi = l >> 5;
    const int kh = wid & 1, sbp = wid >> 1;

    // issue x loads BEFORE the barrier (independent of P1/P2) — T14 issue-early
    float4 xv[8];
    #pragma unroll
    for (int i = 0; i < 8; ++i) {
        int idx = i*256 + t, b = idx >> 4, c = idx & 15;
        xv[i] = *(const float4*)(x + (size_t)(b0 + b)*2048 + s*64 + c*4);
    }

    gridbar(bar + 32);

    {
        char* Tb0 = smem;
        char* Tb1 = smem + 16384;
        char* xl2 = smem + 32768;   // [f>>3][b][8] f16
        char* xr2 = smem + 40960;   // [g>>3][b][8] f16
        const char* Tps = Tp + (size_t)s*65536;

        uint4 tv[4];
        #pragma unroll
        for (int i = 0; i < 4; ++i)
            tv[i] = *(const uint4*)(Tps + (i*256 + t)*16);

        // write pre-loaded x to LDS as f16
        #pragma unroll
        for (int i = 0; i < 8; ++i) {
            int idx = i*256 + t, b = idx >> 4, c = idx & 15;
            float4 v = xv[i];
            h4 w; w[0] = (_Float16)v.x; w[1] = (_Float16)v.y;
                  w[2] = (_Float16)v.z; w[3] = (_Float16)v.w;
            if (c < 8) *(h4*)(xl2 + (c >> 1)*2048 + b*16 + (c & 1)*8) = w;
            else { int c2 = c - 8; *(h4*)(xr2 + (c2 >> 1)*2048 + b*16 + (c2 & 1)*8) = w; }
        }
        #pragma unroll
        for (int i = 0; i < 4; ++i)
            *(uint4*)(Tb0 + (i*256 + t)*16) = tv[i];
        #pragma unroll
        for (int i = 0; i < 4; ++i)
            tv[i] = *(const uint4*)(Tps + 16384 + (i*256 + t)*16);
        __syncthreads();

        // register hoists (all indices compile-time)
        h4 xlh[2][4];
        h8 xrh[2][2];
        #pragma unroll
        for (int sb = 0; sb < 2; ++sb) {
            int b = sbp*64 + sb*32 + lo5;
            #pragma unroll
            for (int c = 0; c < 4; ++c)
                xlh[sb][c] = *(const h4*)(xl2 + c*2048 + b*16 + kh*8);
            #pragma unroll
            for (int gh = 0; gh < 2; ++gh)
                xrh[sb][gh] = *(const h8*)(xr2 + (gh*2 + hi)*2048 + b*16);
        }

        f32x16 acc0 = (f32x16)(0.f), acc1 = (f32x16)(0.f);

        #pragma unroll
        for (int c = 0; c < 4; ++c) {
            const char* Tc = (c & 1) ? Tb1 : Tb0;
            #pragma unroll
            for (int i = 0; i < 8; ++i) {
                int ksl = kh*8 + i;
                h8 bf = *(const h8*)(Tc + ksl*1024 + lo5*32 + hi*16);
                _Float16 x0 = xlh[0][c][i >> 1];
                _Float16 x1 = xlh[1][c][i >> 1];
                h8 z0 = xrh[0][i & 1] * x0;
                acc0 = __builtin_amdgcn_mfma_f32_32x32x16_f16(z0, bf, acc0, 0, 0, 0);
                h8 z1 = xrh[1][i & 1] * x1;
                acc1 = __builtin_amdgcn_mfma_f32_32x32x16_f16(z1, bf, acc1, 0, 0, 0);
            }
            if (c < 3) {
                char* Tn = (c & 1) ? Tb0 : Tb1;
                #pragma unroll
                for (int i = 0; i < 4; ++i)
                    *(uint4*)(Tn + (i*256 + t)*16) = tv[i];
                if (c < 2) {
                    #pragma unroll
                    for (int i = 0; i < 4; ++i)
                        tv[i] = *(const uint4*)(Tps + (c + 2)*16384 + (i*256 + t)*16);
                }
                __syncthreads();
            }
        }

        // k-half reduce via xl2/xr2 (free now)
        __syncthreads();
        if (kh == 1) {
            #pragma unroll
            for (int rq = 0; rq < 4; ++rq) {
                f32x4 p0, p1;
                #pragma unroll
                for (int rr = 0; rr < 4; ++rr) { p0[rr] = acc0[rq*4 + rr]; p1[rr] = acc1[rq*4 + rr]; }
                *(f32x4*)(xl2 + sbp*4096 + rq*1024 + l*16) = p0;
                *(f32x4*)(xr2 + sbp*4096 + rq*1024 + l*16) = p1;
            }
        }
        __syncthreads();
        if (kh == 0) {
            const float bv = bias[s*32 + lo5];
            #pragma unroll
            for (int rq = 0; rq < 4; ++rq) {
                f32x4 p0 = *(const f32x4*)(xl2 + sbp*4096 + rq*1024 + l*16);
                f32x4 p1 = *(const f32x4*)(xr2 + sbp*4096 + rq*1024 + l*16);
                #pragma unroll
                for (int rr = 0; rr < 4; ++rr) {
                    int r = rq*4 + rr;
                    int rowoff = (r & 3) + 8*(r >> 2) + 4*hi;
                    out[(size_t)(b0 + sbp*64 + rowoff)*1024 + s*32 + lo5] = acc0[r] + p0[rr] + bv;
                    out[(size_t)(b0 + sbp*64 + 32 + rowoff)*1024 + s*32 + lo5] = acc1[r] + p1[rr] + bv;
                }
            }
        }
    }
}

extern "C" void kernel_launch(void* const* d_in, const int* in_sizes, int n_in,
                              void* d_out, int out_size, void* d_ws, size_t ws_size,
                              hipStream_t stream) {
    const float* x    = (const float*)d_in[0];
    const float* L    = (const float*)d_in[1];
    const float* R    = (const float*)d_in[2];
    const float* O    = (const float*)d_in[3];
    const float* bias = (const float*)d_in[4];
    float* out = (float*)d_out;

    _Float16* Rb  = (_Float16*)d_ws;                     // 2 MB
    char*     Opp = (char*)d_ws + 2097152;               // 2 MB
    char*     Tp  = (char*)d_ws + 4194304;               // 2 MB
    unsigned* bar = (unsigned*)((char*)d_ws + 6291456);  // 2 barrier counters

    hipMemsetAsync(bar, 0, 256, stream);                 // reset barrier state each call
    fused_kernel<<<dim3(512), dim3(256), 0, stream>>>(x, L, R, O, bias, out,
                                                      Rb, Opp, Tp, bar);
}

// Round 7
// 109.849 us; speedup vs baseline: 2.2831x; 2.2831x over previous
//
#include <hip/hip_runtime.h>
#include <hip/hip_bf16.h>

// B=2048, NF=64, FD=32, S=32, D=32, OD=32
// MEASUREMENT ROUND: round-5 kernels with idempotent REP amplification
// (conv x4, tmake x4, main x3) to surface per-kernel durations in rocprof top-5.
typedef __attribute__((ext_vector_type(4)))  _Float16 h4;
typedef __attribute__((ext_vector_type(8)))  _Float16 h8;
typedef __attribute__((ext_vector_type(4)))  float f32x4;
typedef __attribute__((ext_vector_type(16))) float f32x16;

// ---------------- conv: Rb[s][g][n][a] f16 ; Opp[s][c8][o][kk] ----
__global__ __launch_bounds__(64) void conv_kernel(
    const float* __restrict__ Rg, const float* __restrict__ Og,
    _Float16* __restrict__ Rb, char* __restrict__ Opp)
{
    __shared__ float tile[32][33];
    const int bid = blockIdx.x;
    const int s = bid & 31, q = (bid >> 5) & 31, which = bid >> 10;
    const int t = threadIdx.x, tl = t & 31, th = t >> 5;

    #pragma unroll 1
    for (int rep = 0; rep < 4; ++rep) {
        if (which == 0) {
            #pragma unroll
            for (int j = 0; j < 16; ++j) {
                int ar = 2*j + th;
                tile[tl][ar] = Rg[(((size_t)s*32 + q)*32 + ar)*32 + tl];
            }
            __syncthreads();
            _Float16* dst = Rb + ((size_t)s*32 + q)*1024;
            #pragma unroll
            for (int it = 0; it < 4; ++it) {
                int nr = it*8 + (t >> 3), a0 = (t & 7)*4;
                h4 w;
                #pragma unroll
                for (int k = 0; k < 4; ++k) w[k] = (_Float16)tile[nr][a0 + k];
                *(h4*)(dst + nr*32 + a0) = w;
            }
        } else {
            #pragma unroll
            for (int j = 0; j < 16; ++j) {
                int nr = 2*j + th;
                tile[tl][nr] = Og[(((size_t)s*32 + q)*32 + nr)*32 + tl];
            }
            __syncthreads();
            char* dst = Opp + (size_t)s*65536 + q*2048;
            int o = t & 31, cq = t >> 5;
            #pragma unroll
            for (int it = 0; it < 2; ++it) {
                int c = it*2 + cq;
                h8 w;
                #pragma unroll
                for (int k = 0; k < 8; ++k) w[k] = (_Float16)tile[o][c*8 + k];
                *(h8*)(dst + c*512 + o*16) = w;
            }
        }
        __syncthreads();
    }
}

// ---------------- tmake: Tp[s][ks=f*2+gt][o][kk] ----
__global__ __launch_bounds__(256, 2) void tmake_kernel(
    const float* __restrict__ Lg, const _Float16* __restrict__ Rb,
    const char* __restrict__ Opp, char* __restrict__ Tp)
{
    __shared__ __align__(16) char Wl[65536];
    const int bid = blockIdx.x;
    const int s = bid & 31, f = bid >> 5;
    const int t = threadIdx.x, wid = t >> 6, l = t & 63;
    const int llo = l & 15, lhi = l >> 4;

    #pragma unroll 1
    for (int rep = 0; rep < 4; ++rep) {
        const float* Lsf = Lg + ((size_t)s*32 + f)*1024;
        h8 bfr[2];
        #pragma unroll
        for (int mt = 0; mt < 2; ++mt)
            #pragma unroll
            for (int j = 0; j < 8; ++j)
                bfr[mt][j] = (_Float16)Lsf[(8*lhi + j)*32 + mt*16 + llo];

        const _Float16* Rbs = Rb + (size_t)s*32768;

        #pragma unroll 4
        for (int nt = 0; nt < 16; ++nt) {
            int gnb = (wid*16 + nt)*16;
            h8 af = *(const h8*)(Rbs + (gnb + llo)*32 + 8*lhi);
            int g = gnb >> 5;
            int nbase = (gnb & 31) + 4*lhi;
            #pragma unroll
            for (int mt = 0; mt < 2; ++mt) {
                f32x4 d = __builtin_amdgcn_mfma_f32_16x16x32_f16(af, bfr[mt], (f32x4)(0.f), 0, 0, 0);
                int m = mt*16 + llo;
                h4 w;
                #pragma unroll
                for (int r = 0; r < 4; ++r) w[r] = (_Float16)d[r];
                int byte = (g*2048 + m*64 + nbase*2) ^ ((((g & 7) ^ (m & 7))) << 4);
                *(h4*)(Wl + byte) = w;
            }
        }
        __syncthreads();

        const int ot = wid & 1, kq = wid >> 1;
        const int orow = ot*16 + llo;
        const char* Opps = Opp + (size_t)s*65536;
        f32x4 acc0 = (f32x4)(0.f), acc1 = (f32x4)(0.f);
        #pragma unroll 4
        for (int ksl = 0; ksl < 16; ++ksl) {
            int ks = kq*16 + ksl;
            h8 bf = *(const h8*)(Opps + (ks*4 + lhi)*512 + orow*16);
            {
                int grow = llo;
                int byte = (grow*2048 + ks*64 + lhi*16) ^ ((((grow & 7) ^ (ks & 7))) << 4);
                h8 af = *(const h8*)(Wl + byte);
                acc0 = __builtin_amdgcn_mfma_f32_16x16x32_f16(af, bf, acc0, 0, 0, 0);
            }
            {
                int grow = 16 + llo;
                int byte = (grow*2048 + ks*64 + lhi*16) ^ ((((grow & 7) ^ (ks & 7))) << 4);
                h8 af = *(const h8*)(Wl + byte);
                acc1 = __builtin_amdgcn_mfma_f32_16x16x32_f16(af, bf, acc1, 0, 0, 0);
            }
        }
        __syncthreads();
        if (kq == 1) {
            *(f32x4*)(Wl + ((ot*2 + 0)*64 + l)*16) = acc0;
            *(f32x4*)(Wl + ((ot*2 + 1)*64 + l)*16) = acc1;
        }
        __syncthreads();
        if (kq == 0) {
            acc0 += *(const f32x4*)(Wl + ((ot*2 + 0)*64 + l)*16);
            acc1 += *(const f32x4*)(Wl + ((ot*2 + 1)*64 + l)*16);
            char* Tps = Tp + (size_t)s*65536;
            h4 w0, w1;
            #pragma unroll
            for (int r = 0; r < 4; ++r) { w0[r] = (_Float16)acc0[r]; w1[r] = (_Float16)acc1[r]; }
            *(h4*)(Tps + (f*2 + 0)*1024 + orow*32 + lhi*8) = w0;
            *(h4*)(Tps + (f*2 + 1)*1024 + orow*32 + lhi*8) = w1;
        }
        __syncthreads();
    }
}

// ---------------- main ----
__global__ __launch_bounds__(256, 3) void main_kernel(
    const float* __restrict__ x, const char* __restrict__ Tp,
    const float* __restrict__ bias, float* __restrict__ out)
{
    __shared__ __align__(16) char Tb0[16384];
    __shared__ __align__(16) char Tb1[16384];
    __shared__ __align__(16) char xl2[8192];
    __shared__ __align__(16) char xr2[8192];

    const int bid = blockIdx.x;
    const int s = bid & 31;
    const int b0 = (bid >> 5) * 128;
    const int t = threadIdx.x, wid = t >> 6, l = t & 63;
    const int lo5 = l & 31, hi = l >> 5;
    const int kh = wid & 1, sbp = wid >> 1;

    const char* Tps = Tp + (size_t)s*65536;

    #pragma unroll 1
    for (int rep = 0; rep < 3; ++rep) {
        uint4 tv[4];
        #pragma unroll
        for (int i = 0; i < 4; ++i)
            tv[i] = *(const uint4*)(Tps + (i*256 + t)*16);

        #pragma unroll
        for (int i = 0; i < 8; ++i) {
            int idx = i*256 + t, b = idx >> 4, c = idx & 15;
            float4 v = *(const float4*)(x + (size_t)(b0 + b)*2048 + s*64 + c*4);
            h4 w; w[0] = (_Float16)v.x; w[1] = (_Float16)v.y;
                  w[2] = (_Float16)v.z; w[3] = (_Float16)v.w;
            if (c < 8) *(h4*)(xl2 + (c >> 1)*2048 + b*16 + (c & 1)*8) = w;
            else { int c2 = c - 8; *(h4*)(xr2 + (c2 >> 1)*2048 + b*16 + (c2 & 1)*8) = w; }
        }
        #pragma unroll
        for (int i = 0; i < 4; ++i)
            *(uint4*)(Tb0 + (i*256 + t)*16) = tv[i];
        #pragma unroll
        for (int i = 0; i < 4; ++i)
            tv[i] = *(const uint4*)(Tps + 16384 + (i*256 + t)*16);
        __syncthreads();

        h4 xlh[2][4];
        h8 xrh[2][2];
        #pragma unroll
        for (int sb = 0; sb < 2; ++sb) {
            int b = sbp*64 + sb*32 + lo5;
            #pragma unroll
            for (int c = 0; c < 4; ++c)
                xlh[sb][c] = *(const h4*)(xl2 + c*2048 + b*16 + kh*8);
            #pragma unroll
            for (int gh = 0; gh < 2; ++gh)
                xrh[sb][gh] = *(const h8*)(xr2 + (gh*2 + hi)*2048 + b*16);
        }

        f32x16 acc0 = (f32x16)(0.f), acc1 = (f32x16)(0.f);

        #pragma unroll
        for (int c = 0; c < 4; ++c) {
            const char* Tc = (c & 1) ? Tb1 : Tb0;
            #pragma unroll
            for (int i = 0; i < 8; ++i) {
                int ksl = kh*8 + i;
                h8 bf = *(const h8*)(Tc + ksl*1024 + lo5*32 + hi*16);
                _Float16 x0 = xlh[0][c][i >> 1];
                _Float16 x1 = xlh[1][c][i >> 1];
                h8 z0 = xrh[0][i & 1] * x0;
                acc0 = __builtin_amdgcn_mfma_f32_32x32x16_f16(z0, bf, acc0, 0, 0, 0);
                h8 z1 = xrh[1][i & 1] * x1;
                acc1 = __builtin_amdgcn_mfma_f32_32x32x16_f16(z1, bf, acc1, 0, 0, 0);
            }
            if (c < 3) {
                char* Tn = (c & 1) ? Tb0 : Tb1;
                #pragma unroll
                for (int i = 0; i < 4; ++i)
                    *(uint4*)(Tn + (i*256 + t)*16) = tv[i];
                if (c < 2) {
                    #pragma unroll
                    for (int i = 0; i < 4; ++i)
                        tv[i] = *(const uint4*)(Tps + (c + 2)*16384 + (i*256 + t)*16);
                }
                __syncthreads();
            }
        }

        __syncthreads();
        if (kh == 1) {
            #pragma unroll
            for (int rq = 0; rq < 4; ++rq) {
                f32x4 p0, p1;
                #pragma unroll
                for (int rr = 0; rr < 4; ++rr) { p0[rr] = acc0[rq*4 + rr]; p1[rr] = acc1[rq*4 + rr]; }
                *(f32x4*)(xl2 + sbp*4096 + rq*1024 + l*16) = p0;
                *(f32x4*)(xr2 + sbp*4096 + rq*1024 + l*16) = p1;
            }
        }
        __syncthreads();
        if (kh == 0) {
            const float bv = bias[s*32 + lo5];
            #pragma unroll
            for (int rq = 0; rq < 4; ++rq) {
                f32x4 p0 = *(const f32x4*)(xl2 + sbp*4096 + rq*1024 + l*16);
                f32x4 p1 = *(const f32x4*)(xr2 + sbp*4096 + rq*1024 + l*16);
                #pragma unroll
                for (int rr = 0; rr < 4; ++rr) {
                    int r = rq*4 + rr;
                    int rowoff = (r & 3) + 8*(r >> 2) + 4*hi;
                    out[(size_t)(b0 + sbp*64 + rowoff)*1024 + s*32 + lo5] = acc0[r] + p0[rr] + bv;
                    out[(size_t)(b0 + sbp*64 + 32 + rowoff)*1024 + s*32 + lo5] = acc1[r] + p1[rr] + bv;
                }
            }
        }
        __syncthreads();
    }
}

extern "C" void kernel_launch(void* const* d_in, const int* in_sizes, int n_in,
                              void* d_out, int out_size, void* d_ws, size_t ws_size,
                              hipStream_t stream) {
    const float* x    = (const float*)d_in[0];
    const float* L    = (const float*)d_in[1];
    const float* R    = (const float*)d_in[2];
    const float* O    = (const float*)d_in[3];
    const float* bias = (const float*)d_in[4];
    float* out = (float*)d_out;

    _Float16* Rb  = (_Float16*)d_ws;                 // 2 MB
    char*     Opp = (char*)d_ws + 2097152;           // 2 MB
    char*     Tp  = (char*)d_ws + 4194304;           // 2 MB

    conv_kernel<<<dim3(2048), 64, 0, stream>>>(R, O, Rb, Opp);
    tmake_kernel<<<dim3(1024), 256, 0, stream>>>(L, Rb, Opp, Tp);
    main_kernel<<<dim3(512), 256, 0, stream>>>(x, Tp, bias, out);
}

// Round 8
// 39.167 us; speedup vs baseline: 6.4031x; 2.8046x over previous
//
#include <hip/hip_runtime.h>
#include <hip/hip_bf16.h>

// B=2048, NF=64, FD=32, S=32, D=32, OD=32
typedef __attribute__((ext_vector_type(4)))  _Float16 h4;
typedef __attribute__((ext_vector_type(8)))  _Float16 h8;
typedef __attribute__((ext_vector_type(4)))  float f32x4;
typedef __attribute__((ext_vector_type(16))) float f32x16;

// ---------------- conv: Rb[s][g][n][a] f16 ; Opp[s][c8][o][kk] ----
__global__ __launch_bounds__(64) void conv_kernel(
    const float* __restrict__ Rg, const float* __restrict__ Og,
    _Float16* __restrict__ Rb, char* __restrict__ Opp)
{
    __shared__ float tile[32][33];
    const int bid = blockIdx.x;
    const int s = bid & 31, q = (bid >> 5) & 31, which = bid >> 10;
    const int t = threadIdx.x, tl = t & 31, th = t >> 5;

    if (which == 0) {
        #pragma unroll
        for (int j = 0; j < 16; ++j) {
            int ar = 2*j + th;
            tile[tl][ar] = Rg[(((size_t)s*32 + q)*32 + ar)*32 + tl];
        }
        __syncthreads();
        _Float16* dst = Rb + ((size_t)s*32 + q)*1024;
        #pragma unroll
        for (int it = 0; it < 4; ++it) {
            int nr = it*8 + (t >> 3), a0 = (t & 7)*4;
            h4 w;
            #pragma unroll
            for (int k = 0; k < 4; ++k) w[k] = (_Float16)tile[nr][a0 + k];
            *(h4*)(dst + nr*32 + a0) = w;
        }
    } else {
        #pragma unroll
        for (int j = 0; j < 16; ++j) {
            int nr = 2*j + th;
            tile[tl][nr] = Og[(((size_t)s*32 + q)*32 + nr)*32 + tl];
        }
        __syncthreads();
        char* dst = Opp + (size_t)s*65536 + q*2048;
        int o = t & 31, cq = t >> 5;
        #pragma unroll
        for (int it = 0; it < 2; ++it) {
            int c = it*2 + cq;
            h8 w;
            #pragma unroll
            for (int k = 0; k < 8; ++k) w[k] = (_Float16)tile[o][c*8 + k];
            *(h8*)(dst + c*512 + o*16) = w;
        }
    }
}

// ---------------- tmake: Tp[s][ks=f*2+gt][o][kk] ----
__global__ __launch_bounds__(256, 2) void tmake_kernel(
    const float* __restrict__ Lg, const _Float16* __restrict__ Rb,
    const char* __restrict__ Opp, char* __restrict__ Tp)
{
    __shared__ __align__(16) char Wl[65536];
    const int bid = blockIdx.x;
    const int s = bid & 31, f = bid >> 5;
    const int t = threadIdx.x, wid = t >> 6, l = t & 63;
    const int llo = l & 15, lhi = l >> 4;

    const float* Lsf = Lg + ((size_t)s*32 + f)*1024;
    h8 bfr[2];
    #pragma unroll
    for (int mt = 0; mt < 2; ++mt)
        #pragma unroll
        for (int j = 0; j < 8; ++j)
            bfr[mt][j] = (_Float16)Lsf[(8*lhi + j)*32 + mt*16 + llo];

    const _Float16* Rbs = Rb + (size_t)s*32768;

    #pragma unroll 4
    for (int nt = 0; nt < 16; ++nt) {
        int gnb = (wid*16 + nt)*16;
        h8 af = *(const h8*)(Rbs + (gnb + llo)*32 + 8*lhi);
        int g = gnb >> 5;
        int nbase = (gnb & 31) + 4*lhi;
        #pragma unroll
        for (int mt = 0; mt < 2; ++mt) {
            f32x4 d = __builtin_amdgcn_mfma_f32_16x16x32_f16(af, bfr[mt], (f32x4)(0.f), 0, 0, 0);
            int m = mt*16 + llo;
            h4 w;
            #pragma unroll
            for (int r = 0; r < 4; ++r) w[r] = (_Float16)d[r];
            int byte = (g*2048 + m*64 + nbase*2) ^ ((((g & 7) ^ (m & 7))) << 4);
            *(h4*)(Wl + byte) = w;
        }
    }
    __syncthreads();

    const int ot = wid & 1, kq = wid >> 1;
    const int orow = ot*16 + llo;
    const char* Opps = Opp + (size_t)s*65536;
    f32x4 acc0 = (f32x4)(0.f), acc1 = (f32x4)(0.f);
    #pragma unroll 4
    for (int ksl = 0; ksl < 16; ++ksl) {
        int ks = kq*16 + ksl;
        h8 bf = *(const h8*)(Opps + (ks*4 + lhi)*512 + orow*16);
        {
            int grow = llo;
            int byte = (grow*2048 + ks*64 + lhi*16) ^ ((((grow & 7) ^ (ks & 7))) << 4);
            h8 af = *(const h8*)(Wl + byte);
            acc0 = __builtin_amdgcn_mfma_f32_16x16x32_f16(af, bf, acc0, 0, 0, 0);
        }
        {
            int grow = 16 + llo;
            int byte = (grow*2048 + ks*64 + lhi*16) ^ ((((grow & 7) ^ (ks & 7))) << 4);
            h8 af = *(const h8*)(Wl + byte);
            acc1 = __builtin_amdgcn_mfma_f32_16x16x32_f16(af, bf, acc1, 0, 0, 0);
        }
    }
    __syncthreads();
    if (kq == 1) {
        *(f32x4*)(Wl + ((ot*2 + 0)*64 + l)*16) = acc0;
        *(f32x4*)(Wl + ((ot*2 + 1)*64 + l)*16) = acc1;
    }
    __syncthreads();
    if (kq == 0) {
        acc0 += *(const f32x4*)(Wl + ((ot*2 + 0)*64 + l)*16);
        acc1 += *(const f32x4*)(Wl + ((ot*2 + 1)*64 + l)*16);
        char* Tps = Tp + (size_t)s*65536;
        h4 w0, w1;
        #pragma unroll
        for (int r = 0; r < 4; ++r) { w0[r] = (_Float16)acc0[r]; w1[r] = (_Float16)acc1[r]; }
        *(h4*)(Tps + (f*2 + 0)*1024 + orow*32 + lhi*8) = w0;
        *(h4*)(Tps + (f*2 + 1)*1024 + orow*32 + lhi*8) = w1;
    }
}

// ---------------- main: out[b,s,o] = sum_k (xL[b,f]*xR[b,g]) * Tp[s][k][o]
// grid 1024: btile = bid&31 (XCD = btile%8: all s of a b-range on ONE XCD),
// s = bid>>5. BT=64, 4 waves = (kh = wid&1) x (sbp = wid>>1). 40KB LDS -> 4 blk/CU.
__global__ __launch_bounds__(256, 4) void main_kernel(
    const float* __restrict__ x, const char* __restrict__ Tp,
    const float* __restrict__ bias, float* __restrict__ out)
{
    __shared__ __align__(16) char Tb0[16384];
    __shared__ __align__(16) char Tb1[16384];
    __shared__ __align__(16) char xbuf[8192];   // [0,4K)=xl [f>>3][b][8], [4K,8K)=xr

    const int bid = blockIdx.x;
    const int btile = bid & 31, s = bid >> 5;
    const int b0 = btile * 64;
    const int t = threadIdx.x, wid = t >> 6, l = t & 63;
    const int lo5 = l & 31, hi = l >> 5;
    const int kh = wid & 1, sbp = wid >> 1;

    const char* Tps = Tp + (size_t)s*65536;

    // issue chunk-0 + x loads up front
    uint4 tv[4];
    #pragma unroll
    for (int i = 0; i < 4; ++i)
        tv[i] = *(const uint4*)(Tps + (i*256 + t)*16);

    float4 xv[4];
    #pragma unroll
    for (int i = 0; i < 4; ++i) {
        int idx = i*256 + t, b = idx >> 4, c = idx & 15;
        xv[i] = *(const float4*)(x + (size_t)(b0 + b)*2048 + s*64 + c*4);
    }

    #pragma unroll
    for (int i = 0; i < 4; ++i)
        *(uint4*)(Tb0 + (i*256 + t)*16) = tv[i];
    #pragma unroll
    for (int i = 0; i < 4; ++i)                 // issue chunk-1
        tv[i] = *(const uint4*)(Tps + 16384 + (i*256 + t)*16);

    #pragma unroll
    for (int i = 0; i < 4; ++i) {
        int idx = i*256 + t, b = idx >> 4, c = idx & 15;
        float4 v = xv[i];
        h4 w; w[0] = (_Float16)v.x; w[1] = (_Float16)v.y;
              w[2] = (_Float16)v.z; w[3] = (_Float16)v.w;
        if (c < 8) *(h4*)(xbuf + (c >> 1)*1024 + b*16 + (c & 1)*8) = w;
        else { int c2 = c - 8; *(h4*)(xbuf + 4096 + (c2 >> 1)*1024 + b*16 + (c2 & 1)*8) = w; }
    }
    __syncthreads();

    // register hoists (compile-time indices)
    const int b = sbp*32 + lo5;
    h4 xlh[4];
    #pragma unroll
    for (int c = 0; c < 4; ++c)
        xlh[c] = *(const h4*)(xbuf + c*1024 + b*16 + kh*8);
    h8 xrh[2];
    #pragma unroll
    for (int gh = 0; gh < 2; ++gh)
        xrh[gh] = *(const h8*)(xbuf + 4096 + (gh*2 + hi)*1024 + b*16);

    f32x16 acc_e = (f32x16)(0.f), acc_o = (f32x16)(0.f);

    #pragma unroll
    for (int c = 0; c < 4; ++c) {
        const char* Tc = (c & 1) ? Tb1 : Tb0;
        #pragma unroll
        for (int i = 0; i < 8; ++i) {
            int ksl = kh*8 + i;
            h8 bf = *(const h8*)(Tc + ksl*1024 + lo5*32 + hi*16);
            _Float16 xs = xlh[c][i >> 1];
            h8 z = xrh[i & 1] * xs;
            if (i & 1) acc_o = __builtin_amdgcn_mfma_f32_32x32x16_f16(z, bf, acc_o, 0, 0, 0);
            else       acc_e = __builtin_amdgcn_mfma_f32_32x32x16_f16(z, bf, acc_e, 0, 0, 0);
        }
        if (c < 3) {
            char* Tn = (c & 1) ? Tb0 : Tb1;
            #pragma unroll
            for (int i = 0; i < 4; ++i)
                *(uint4*)(Tn + (i*256 + t)*16) = tv[i];
            if (c < 2) {
                #pragma unroll
                for (int i = 0; i < 4; ++i)
                    tv[i] = *(const uint4*)(Tps + (c + 2)*16384 + (i*256 + t)*16);
            }
            __syncthreads();
        }
    }

    f32x16 acc = acc_e + acc_o;

    // epilogue: stash per-kh tiles in Tb0 (free after chunk-2 barrier), then
    // vectorized reduce+bias+store. Tile kh at Tb0 + kh*8192: [row64][col32] f32.
    #pragma unroll
    for (int r = 0; r < 16; ++r) {
        int row = sbp*32 + (r & 3) + 8*(r >> 2) + 4*hi;
        *(float*)(Tb0 + kh*8192 + row*128 + lo5*4) = acc[r];
    }
    __syncthreads();

    const float* bias_s = bias + s*32;
    #pragma unroll
    for (int k = 0; k < 2; ++k) {
        int u = k*256 + t;                     // 16B unit, lanes contiguous
        int row = u >> 3, colq = u & 7;
        f32x4 v0 = *(const f32x4*)(Tb0 + u*16);
        f32x4 v1 = *(const f32x4*)(Tb0 + 8192 + u*16);
        f32x4 bv = *(const f32x4*)(bias_s + colq*4);
        f32x4 res = v0 + v1 + bv;
        *(f32x4*)(out + (size_t)(b0 + row)*1024 + s*32 + colq*4) = res;
    }
}

extern "C" void kernel_launch(void* const* d_in, const int* in_sizes, int n_in,
                              void* d_out, int out_size, void* d_ws, size_t ws_size,
                              hipStream_t stream) {
    const float* x    = (const float*)d_in[0];
    const float* L    = (const float*)d_in[1];
    const float* R    = (const float*)d_in[2];
    const float* O    = (const float*)d_in[3];
    const float* bias = (const float*)d_in[4];
    float* out = (float*)d_out;

    _Float16* Rb  = (_Float16*)d_ws;                 // 2 MB
    char*     Opp = (char*)d_ws + 2097152;           // 2 MB
    char*     Tp  = (char*)d_ws + 4194304;           // 2 MB

    conv_kernel<<<dim3(2048), 64, 0, stream>>>(R, O, Rb, Opp);
    tmake_kernel<<<dim3(1024), 256, 0, stream>>>(L, Rb, Opp, Tp);
    main_kernel<<<dim3(1024), 256, 0, stream>>>(x, Tp, bias, out);
}

// Round 9
// 28.895 us; speedup vs baseline: 8.6792x; 1.3555x over previous
//
#include <hip/hip_runtime.h>
#include <hip/hip_bf16.h>

// B=2048, NF=64, FD=32, S=32, D=32, OD=32
typedef __attribute__((ext_vector_type(4)))  _Float16 h4;
typedef __attribute__((ext_vector_type(8)))  _Float16 h8;
typedef __attribute__((ext_vector_type(4)))  float f32x4;
typedef __attribute__((ext_vector_type(16))) float f32x16;

// s-decode: sp = bid&31 -> s = ((sp&7)<<2)|(sp>>3)  => XCD(bid%8) = s>>2
// (each XCD owns 4 consecutive s => 512B-contiguous out columns per XCD)
__device__ __forceinline__ int sdecode(int sp) { return ((sp & 7) << 2) | (sp >> 3); }

// ---------------- conv: Rb[s][g][n][a] f16 ; Opp[s][c8][o][kk] ----
__global__ __launch_bounds__(64) void conv_kernel(
    const float* __restrict__ Rg, const float* __restrict__ Og,
    _Float16* __restrict__ Rb, char* __restrict__ Opp)
{
    __shared__ float tile[32][33];
    const int bid = blockIdx.x;
    const int s = sdecode(bid & 31), q = (bid >> 5) & 31, which = bid >> 10;
    const int t = threadIdx.x, tl = t & 31, th = t >> 5;

    if (which == 0) {
        #pragma unroll
        for (int j = 0; j < 16; ++j) {
            int ar = 2*j + th;
            tile[tl][ar] = Rg[(((size_t)s*32 + q)*32 + ar)*32 + tl];
        }
        __syncthreads();
        _Float16* dst = Rb + ((size_t)s*32 + q)*1024;
        #pragma unroll
        for (int it = 0; it < 4; ++it) {
            int nr = it*8 + (t >> 3), a0 = (t & 7)*4;
            h4 w;
            #pragma unroll
            for (int k = 0; k < 4; ++k) w[k] = (_Float16)tile[nr][a0 + k];
            *(h4*)(dst + nr*32 + a0) = w;
        }
    } else {
        #pragma unroll
        for (int j = 0; j < 16; ++j) {
            int nr = 2*j + th;
            tile[tl][nr] = Og[(((size_t)s*32 + q)*32 + nr)*32 + tl];
        }
        __syncthreads();
        char* dst = Opp + (size_t)s*65536 + q*2048;
        int o = t & 31, cq = t >> 5;
        #pragma unroll
        for (int it = 0; it < 2; ++it) {
            int c = it*2 + cq;
            h8 w;
            #pragma unroll
            for (int k = 0; k < 8; ++k) w[k] = (_Float16)tile[o][c*8 + k];
            *(h8*)(dst + c*512 + o*16) = w;
        }
    }
}

// ---------------- tmake: Tp[s][ks=f*2+gt][o][kk] ----
__global__ __launch_bounds__(256, 2) void tmake_kernel(
    const float* __restrict__ Lg, const _Float16* __restrict__ Rb,
    const char* __restrict__ Opp, char* __restrict__ Tp)
{
    __shared__ __align__(16) char Wl[65536];
    const int bid = blockIdx.x;
    const int s = sdecode(bid & 31), f = bid >> 5;
    const int t = threadIdx.x, wid = t >> 6, l = t & 63;
    const int llo = l & 15, lhi = l >> 4;

    const float* Lsf = Lg + ((size_t)s*32 + f)*1024;
    h8 bfr[2];
    #pragma unroll
    for (int mt = 0; mt < 2; ++mt)
        #pragma unroll
        for (int j = 0; j < 8; ++j)
            bfr[mt][j] = (_Float16)Lsf[(8*lhi + j)*32 + mt*16 + llo];

    const _Float16* Rbs = Rb + (size_t)s*32768;

    #pragma unroll 4
    for (int nt = 0; nt < 16; ++nt) {
        int gnb = (wid*16 + nt)*16;
        h8 af = *(const h8*)(Rbs + (gnb + llo)*32 + 8*lhi);
        int g = gnb >> 5;
        int nbase = (gnb & 31) + 4*lhi;
        #pragma unroll
        for (int mt = 0; mt < 2; ++mt) {
            f32x4 d = __builtin_amdgcn_mfma_f32_16x16x32_f16(af, bfr[mt], (f32x4)(0.f), 0, 0, 0);
            int m = mt*16 + llo;
            h4 w;
            #pragma unroll
            for (int r = 0; r < 4; ++r) w[r] = (_Float16)d[r];
            int byte = (g*2048 + m*64 + nbase*2) ^ ((((g & 7) ^ (m & 7))) << 4);
            *(h4*)(Wl + byte) = w;
        }
    }
    __syncthreads();

    const int ot = wid & 1, kq = wid >> 1;
    const int orow = ot*16 + llo;
    const char* Opps = Opp + (size_t)s*65536;
    f32x4 acc0 = (f32x4)(0.f), acc1 = (f32x4)(0.f);
    #pragma unroll 4
    for (int ksl = 0; ksl < 16; ++ksl) {
        int ks = kq*16 + ksl;
        h8 bf = *(const h8*)(Opps + (ks*4 + lhi)*512 + orow*16);
        {
            int grow = llo;
            int byte = (grow*2048 + ks*64 + lhi*16) ^ ((((grow & 7) ^ (ks & 7))) << 4);
            h8 af = *(const h8*)(Wl + byte);
            acc0 = __builtin_amdgcn_mfma_f32_16x16x32_f16(af, bf, acc0, 0, 0, 0);
        }
        {
            int grow = 16 + llo;
            int byte = (grow*2048 + ks*64 + lhi*16) ^ ((((grow & 7) ^ (ks & 7))) << 4);
            h8 af = *(const h8*)(Wl + byte);
            acc1 = __builtin_amdgcn_mfma_f32_16x16x32_f16(af, bf, acc1, 0, 0, 0);
        }
    }
    __syncthreads();
    if (kq == 1) {
        *(f32x4*)(Wl + ((ot*2 + 0)*64 + l)*16) = acc0;
        *(f32x4*)(Wl + ((ot*2 + 1)*64 + l)*16) = acc1;
    }
    __syncthreads();
    if (kq == 0) {
        acc0 += *(const f32x4*)(Wl + ((ot*2 + 0)*64 + l)*16);
        acc1 += *(const f32x4*)(Wl + ((ot*2 + 1)*64 + l)*16);
        char* Tps = Tp + (size_t)s*65536;
        h4 w0, w1;
        #pragma unroll
        for (int r = 0; r < 4; ++r) { w0[r] = (_Float16)acc0[r]; w1[r] = (_Float16)acc1[r]; }
        *(h4*)(Tps + (f*2 + 0)*1024 + orow*32 + lhi*8) = w0;
        *(h4*)(Tps + (f*2 + 1)*1024 + orow*32 + lhi*8) = w1;
    }
}

// ---------------- main v3: out[b,s,o] = sum_ks Z * Tp[s][ks][o]
// grid 512 (sp = bid&31, btile = bid>>5, BT=128), 256 thr = 4 waves.
// x entirely in registers (lane-local rows); T[s] staged once; ONE barrier;
// 64-step K loop (1 ds_read + 2 MFMA, acc ILP=2); vectorized LDS epilogue.
__global__ __launch_bounds__(256, 2) void main_kernel(
    const float* __restrict__ x, const char* __restrict__ Tp,
    const float* __restrict__ bias, float* __restrict__ out)
{
    __shared__ __align__(16) char Tl[65536];

    const int bid = blockIdx.x;
    const int s = sdecode(bid & 31);
    const int b0 = (bid >> 5) * 128;
    const int t = threadIdx.x, wid = t >> 6, l = t & 63;
    const int lo5 = l & 31, hi = l >> 5;

    const char* Tps = Tp + (size_t)s*65536;

    // ---- stage T[s] -> LDS (two reg batches of 8x16B/thread) ----
    uint4 tv[8];
    #pragma unroll
    for (int i = 0; i < 8; ++i)
        tv[i] = *(const uint4*)(Tps + (i*256 + t)*16);

    // ---- per-lane x row loads (lane owns out-row b = b0 + wid*32 + lo5) ----
    const float* xrow = x + (size_t)(b0 + wid*32 + lo5)*2048 + s*64;
    float4 xlv[8];
    #pragma unroll
    for (int i = 0; i < 8; ++i) xlv[i] = *(const float4*)(xrow + i*4);
    const float* xrp = xrow + 32 + hi*8;        // g-range for this lane's k-half
    float4 xr00 = *(const float4*)(xrp);        // g = hi*8 .. +3
    float4 xr01 = *(const float4*)(xrp + 4);    // g = hi*8+4 .. +7
    float4 xr10 = *(const float4*)(xrp + 16);   // g = 16+hi*8 .. +3
    float4 xr11 = *(const float4*)(xrp + 20);   // g = 16+hi*8+4 .. +7

    #pragma unroll
    for (int i = 0; i < 8; ++i)
        *(uint4*)(Tl + (i*256 + t)*16) = tv[i];
    #pragma unroll
    for (int i = 0; i < 8; ++i)
        tv[i] = *(const uint4*)(Tps + ((i + 8)*256 + t)*16);

    // convert x to f16 (overlaps second staging batch)
    h4 xlh[8];
    #pragma unroll
    for (int i = 0; i < 8; ++i) {
        xlh[i][0] = (_Float16)xlv[i].x; xlh[i][1] = (_Float16)xlv[i].y;
        xlh[i][2] = (_Float16)xlv[i].z; xlh[i][3] = (_Float16)xlv[i].w;
    }
    h8 xr_a, xr_b;
    xr_a[0] = (_Float16)xr00.x; xr_a[1] = (_Float16)xr00.y;
    xr_a[2] = (_Float16)xr00.z; xr_a[3] = (_Float16)xr00.w;
    xr_a[4] = (_Float16)xr01.x; xr_a[5] = (_Float16)xr01.y;
    xr_a[6] = (_Float16)xr01.z; xr_a[7] = (_Float16)xr01.w;
    xr_b[0] = (_Float16)xr10.x; xr_b[1] = (_Float16)xr10.y;
    xr_b[2] = (_Float16)xr10.z; xr_b[3] = (_Float16)xr10.w;
    xr_b[4] = (_Float16)xr11.x; xr_b[5] = (_Float16)xr11.y;
    xr_b[6] = (_Float16)xr11.z; xr_b[7] = (_Float16)xr11.w;

    #pragma unroll
    for (int i = 0; i < 8; ++i)
        *(uint4*)(Tl + ((i + 8)*256 + t)*16) = tv[i];
    __syncthreads();

    // ---- K loop: 64 steps, 1 ds_read_b128 + 2 MFMA (even/odd acc chains) ----
    f32x16 acc_e = (f32x16)(0.f), acc_o = (f32x16)(0.f);
    #pragma unroll
    for (int ksl = 0; ksl < 64; ++ksl) {
        h8 bf = *(const h8*)(Tl + ksl*1024 + lo5*32 + hi*16);
        _Float16 xs = xlh[ksl >> 3][(ksl >> 1) & 3];
        if (ksl & 1) {
            h8 z = xr_b * xs;
            acc_o = __builtin_amdgcn_mfma_f32_32x32x16_f16(z, bf, acc_o, 0, 0, 0);
        } else {
            h8 z = xr_a * xs;
            acc_e = __builtin_amdgcn_mfma_f32_32x32x16_f16(z, bf, acc_e, 0, 0, 0);
        }
    }
    f32x16 acc = acc_e + acc_o;

    // ---- epilogue: stash tiles in Tl (dead), vectorized f32x4 stores ----
    __syncthreads();
    #pragma unroll
    for (int r = 0; r < 16; ++r) {
        int row = (r & 3) + 8*(r >> 2) + 4*hi;          // 32x32 C/D row map
        *(float*)(Tl + wid*4096 + row*128 + lo5*4) = acc[r];
    }
    __syncthreads();

    const float* bias_s = bias + s*32;
    #pragma unroll
    for (int i = 0; i < 4; ++i) {
        int u = i*256 + t;                // row = u>>3 (0..127), colq = u&7
        int row = u >> 3, colq = u & 7;
        f32x4 v = *(const f32x4*)(Tl + u*16);
        f32x4 bv = *(const f32x4*)(bias_s + colq*4);
        *(f32x4*)(out + (size_t)(b0 + row)*1024 + s*32 + colq*4) = v + bv;
    }
}

extern "C" void kernel_launch(void* const* d_in, const int* in_sizes, int n_in,
                              void* d_out, int out_size, void* d_ws, size_t ws_size,
                              hipStream_t stream) {
    const float* x    = (const float*)d_in[0];
    const float* L    = (const float*)d_in[1];
    const float* R    = (const float*)d_in[2];
    const float* O    = (const float*)d_in[3];
    const float* bias = (const float*)d_in[4];
    float* out = (float*)d_out;

    _Float16* Rb  = (_Float16*)d_ws;                 // 2 MB
    char*     Opp = (char*)d_ws + 2097152;           // 2 MB
    char*     Tp  = (char*)d_ws + 4194304;           // 2 MB

    conv_kernel<<<dim3(2048), 64, 0, stream>>>(R, O, Rb, Opp);
    tmake_kernel<<<dim3(1024), 256, 0, stream>>>(L, Rb, Opp, Tp);
    main_kernel<<<dim3(512), 256, 0, stream>>>(x, Tp, bias, out);
}